// Round 4
// baseline (495.004 us; speedup 1.0000x reference)
//
#include <hip/hip_runtime.h>
#include <hip/hip_bf16.h>
#include <hip/hip_fp16.h>
#include <math.h>

typedef short s16x8 __attribute__((ext_vector_type(8)));
typedef float f32x4 __attribute__((ext_vector_type(4)));
typedef unsigned short u16x4 __attribute__((ext_vector_type(4)));

#define CCH 256
#define SEQ 4096
#define NB 4
#define KVB 32

static __device__ __forceinline__ unsigned short f2bf(float f) {
  union { float f; unsigned int u; } v; v.f = f;
  unsigned int u = v.u;
  unsigned int r = u + 0x7FFFu + ((u >> 16) & 1u);   // RNE
  return (unsigned short)(r >> 16);
}

// ---------------- cvt_w: fp32 -> bf16, 4 elems/thread ----------------
__global__ __launch_bounds__(256) void cvt_w(const float* __restrict__ w,
                                             unsigned short* __restrict__ wb) {
  int i = blockIdx.x * 256 + threadIdx.x;
  float4 v = ((const float4*)w)[i];
  u16x4 r;
  r.x = f2bf(v.x); r.y = f2bf(v.y); r.z = f2bf(v.z); r.w = f2bf(v.w);
  ((u16x4*)wb)[i] = r;
}

// ---------------- cvt_x: x[b][c][s] fp32 -> xb[b][s][c] bf16 (LDS transpose) ------
__global__ __launch_bounds__(256) void cvt_x(const float* __restrict__ x,
                                             unsigned short* __restrict__ xb) {
  __shared__ unsigned short T[64][72];
  int b = blockIdx.z, ct = blockIdx.y, st = blockIdx.x;
  int c0 = ct * 64, s0 = st * 64;
  int tid = threadIdx.x;
  #pragma unroll
  for (int i = 0; i < 4; i++) {
    int idx = tid + i * 256;
    int cr = idx >> 4, c4 = idx & 15;
    float4 v = *(const float4*)&x[((size_t)b * CCH + c0 + cr) * SEQ + s0 + c4 * 4];
    #pragma unroll
    for (int j = 0; j < 4; j++) {
      int s = c4 * 4 + j;
      int colp = cr ^ ((((s) >> 1) & 7) << 3);
      float fv = (j == 0) ? v.x : (j == 1) ? v.y : (j == 2) ? v.z : v.w;
      T[s][colp] = f2bf(fv);
    }
  }
  __syncthreads();
  #pragma unroll
  for (int i = 0; i < 2; i++) {
    int idx = tid + i * 256;
    int sr = idx >> 3, ch = idx & 7;
    int chp = ch ^ ((sr >> 1) & 7);
    s16x8 v = *(const s16x8*)&T[sr][chp * 8];
    *(s16x8*)&xb[((size_t)b * SEQ + s0 + sr) * CCH + c0 + ch * 8] = v;
  }
}

// ---------------- qk_proj: block = 32 s-rows; waves 0,1 -> q, waves 2,3 -> k ----------
__global__ __launch_bounds__(256) void qk_proj(
    const unsigned short* __restrict__ xb, const unsigned short* __restrict__ wqkb,
    const float* __restrict__ bias,
    unsigned short* __restrict__ qb, unsigned short* __restrict__ kb)
{
  int b = blockIdx.y, st = blockIdx.x;   // st 0..127
  int tid = threadIdx.x, w = tid >> 6, l = tid & 63, l15 = l & 15, lg = l >> 4;
  int row0 = st * 32 + (w & 1) * 16;
  int osel = w >> 1;                     // 0=q 1=k

  const unsigned short* xp = xb + ((size_t)b * SEQ + row0 + l15) * CCH + lg * 8;
  s16x8 af[8];
  #pragma unroll
  for (int t = 0; t < 8; t++) af[t] = *(const s16x8*)(xp + t * 32);

  unsigned short* dst = osel ? kb : qb;
  #pragma unroll
  for (int ot = 0; ot < 16; ot++) {
    int orow = osel * 256 + ot * 16;
    f32x4 acc = (f32x4){0.f, 0.f, 0.f, 0.f};
    #pragma unroll
    for (int t = 0; t < 8; t++) {
      s16x8 wf = *(const s16x8*)&wqkb[(size_t)(orow + l15) * CCH + t * 32 + lg * 8];
      acc = __builtin_amdgcn_mfma_f32_16x16x32_bf16(af[t], wf, acc, 0, 0, 0);
    }
    float bi = bias[orow + l15];
    int ch = ot * 16 + l15;
    #pragma unroll
    for (int r = 0; r < 4; r++) {
      int srow = row0 + lg * 4 + r;
      dst[((size_t)b * SEQ + srow) * CCH + ch] = f2bf(acc[r] + bi);
    }
  }
}

// ---------------- v_proj: block = 32 s; wave w -> 64 out-ch; v -> [b][c][s] ----------
__global__ __launch_bounds__(256) void v_proj(
    const unsigned short* __restrict__ xb, const unsigned short* __restrict__ wqkb,
    const float* __restrict__ bias, unsigned short* __restrict__ vb)
{
  int b = blockIdx.y, st = blockIdx.x;   // st 0..127
  int tid = threadIdx.x, w = tid >> 6, l = tid & 63, l15 = l & 15, lg = l >> 4;
  int sbase = st * 32, obase = w * 64;

  f32x4 acc[4][2];
  #pragma unroll
  for (int i = 0; i < 4; i++)
    #pragma unroll
    for (int j = 0; j < 2; j++) acc[i][j] = (f32x4){0.f, 0.f, 0.f, 0.f};

  const unsigned short* xrow = xb + ((size_t)b * SEQ + sbase) * CCH;
  #pragma unroll
  for (int kt = 0; kt < 8; kt++) {
    s16x8 afr[4], bfr[2];
    #pragma unroll
    for (int ot = 0; ot < 4; ot++)
      afr[ot] = *(const s16x8*)&wqkb[(size_t)(512 + obase + ot * 16 + l15) * CCH + kt * 32 + lg * 8];
    #pragma unroll
    for (int sj = 0; sj < 2; sj++)
      bfr[sj] = *(const s16x8*)&xrow[(size_t)(sj * 16 + l15) * CCH + kt * 32 + lg * 8];
    #pragma unroll
    for (int ot = 0; ot < 4; ot++)
      #pragma unroll
      for (int sj = 0; sj < 2; sj++)
        acc[ot][sj] = __builtin_amdgcn_mfma_f32_16x16x32_bf16(afr[ot], bfr[sj], acc[ot][sj], 0, 0, 0);
  }

  #pragma unroll
  for (int ot = 0; ot < 4; ot++) {
    #pragma unroll
    for (int r = 0; r < 4; r++) {
      int o = obase + ot * 16 + lg * 4 + r;
      float bi = bias[512 + o];
      #pragma unroll
      for (int sj = 0; sj < 2; sj++) {
        int s = sbase + sj * 16 + l15;
        vb[((size_t)b * CCH + o) * SEQ + s] = f2bf(acc[ot][sj][r] + bi);
      }
    }
  }
}

// ---------------- attn: single-buffer LDS + reg-staged prefetch, KV-split NSPLIT ------
template<int NSPLIT>
__global__ __launch_bounds__(256, 4) void attn_kernel(
    const unsigned short* __restrict__ qb,
    const unsigned short* __restrict__ kb,
    const unsigned short* __restrict__ vb,
    __half* __restrict__ pacc, float* __restrict__ llp)
{
  constexpr int KVLEN = SEQ / NSPLIT;
  constexpr int NT = KVLEN / KVB;
  __shared__ __align__(16) unsigned short Ks[KVB * CCH];     // 16KB
  __shared__ __align__(16) unsigned short Vs[CCH * KVB];     // 16KB
  __shared__ __align__(16) unsigned short plds[4][16][48];   // 6KB

  int b = blockIdx.z, kvh = blockIdx.y, qt = blockIdx.x;
  int tid = threadIdx.x, w = tid >> 6, l = tid & 63;
  int l15 = l & 15, lg = l >> 4, s3 = l15 & 7;

  int qrow0 = qt * 64 + w * 16;
  const unsigned short* qptr = qb + ((size_t)b * SEQ + qrow0 + l15) * CCH + lg * 8;
  s16x8 qf[8];
  #pragma unroll
  for (int t = 0; t < 8; t++) qf[t] = *(const s16x8*)(qptr + t * 32);

  f32x4 oacc[16];
  #pragma unroll
  for (int i = 0; i < 16; i++) oacc[i] = (f32x4){0.f, 0.f, 0.f, 0.f};
  float ll[4] = {0.f, 0.f, 0.f, 0.f};

  // staging geometry: linear global chunks, swizzled LDS dests
  int ck = tid & 31, rk = tid >> 5;            // K: rows rk+8i, 32 chunks/row
  int gk = rk * CCH + ck * 8;
  int sk = rk * CCH + ((ck ^ (rk & 7)) * 8);   // (rk+8i)&7 == rk&7
  int cv = tid & 3,  rv = tid >> 2;            // V: rows rv+64i, 4 chunks/row
  int gv = rv * SEQ + cv * 8;
  int sv = rv * KVB + ((cv ^ (rv & 3)) * 8);   // (rv+64i)&3 == rv&3

  const unsigned short* kbb = kb + (size_t)b * SEQ * CCH + (size_t)kvh * KVLEN * CCH;
  const unsigned short* vbb = vb + (size_t)b * CCH * SEQ + kvh * KVLEN;

  uint4 kreg[4], vreg[4];
  auto loadrg = [&](int t) {
    const unsigned short* kp = kbb + (size_t)t * KVB * CCH + gk;
    const unsigned short* vp = vbb + t * KVB + gv;
    #pragma unroll
    for (int i = 0; i < 4; i++) kreg[i] = *(const uint4*)(kp + i * (8 * CCH));
    #pragma unroll
    for (int i = 0; i < 4; i++) vreg[i] = *(const uint4*)(vp + (size_t)i * (64 * SEQ));
  };
  auto wrlds = [&]() {
    #pragma unroll
    for (int i = 0; i < 4; i++) *(uint4*)&Ks[sk + i * (8 * CCH)] = kreg[i];
    #pragma unroll
    for (int i = 0; i < 4; i++) *(uint4*)&Vs[sv + i * (64 * KVB)] = vreg[i];
  };

  loadrg(0);
  wrlds();                      // compiler inserts vmcnt wait (RAW on kreg/vreg)
  if (NT > 1) loadrg(1);        // compiler handles WAR vs ds_writes
  asm volatile("s_waitcnt lgkmcnt(0)" ::: "memory");
  __builtin_amdgcn_s_barrier();
  __builtin_amdgcn_sched_barrier(0);

  for (int t = 0; t < NT; t++) {
    // ---- QK^T ----
    f32x4 sacc[2];
    sacc[0] = (f32x4){0.f, 0.f, 0.f, 0.f};
    sacc[1] = (f32x4){0.f, 0.f, 0.f, 0.f};
    __builtin_amdgcn_s_setprio(1);
    #pragma unroll
    for (int kt = 0; kt < 2; kt++) {
      int rowoff = (kt * 16 + l15) * CCH;
      #pragma unroll
      for (int tt = 0; tt < 8; tt++) {
        s16x8 kf = *(const s16x8*)&Ks[rowoff + (((tt * 4 + lg) ^ s3)) * 8];
        sacc[kt] = __builtin_amdgcn_mfma_f32_16x16x32_bf16(qf[tt], kf, sacc[kt], 0, 0, 0);
      }
    }
    __builtin_amdgcn_s_setprio(0);

    // ---- fixed-shift softmax (no reduction) ----
    #pragma unroll
    for (int kt = 0; kt < 2; kt++)
      #pragma unroll
      for (int r = 0; r < 4; r++) {
        float p = exp2f(fmaf(sacc[kt][r], 0.09016844f, -11.5415602f));
        ll[r] += p;
        plds[w][lg * 4 + r][kt * 16 + l15] = f2bf(p);
      }

    // ---- PV ----
    s16x8 pa = *(const s16x8*)&plds[w][l15][lg * 8];
    __builtin_amdgcn_s_setprio(1);
    #pragma unroll
    for (int dt = 0; dt < 16; dt++) {
      s16x8 vf = *(const s16x8*)&Vs[(dt * 16 + l15) * KVB + ((lg ^ (l15 & 3)) * 8)];
      oacc[dt] = __builtin_amdgcn_mfma_f32_16x16x32_bf16(pa, vf, oacc[dt], 0, 0, 0);
    }
    __builtin_amdgcn_s_setprio(0);

    if (t + 1 < NT) {
      __builtin_amdgcn_s_barrier();          // all waves done reading Ks/Vs
      __builtin_amdgcn_sched_barrier(0);
      wrlds();                               // tile t+1 -> LDS
      if (t + 2 < NT) loadrg(t + 2);         // prefetch t+2 into regs
      asm volatile("s_waitcnt lgkmcnt(0)" ::: "memory");
      __builtin_amdgcn_s_barrier();          // writes visible
      __builtin_amdgcn_sched_barrier(0);
    }
  }

  // ---- epilogue: partial row-sums + fp16 partial O ----
  size_t pbase = (size_t)(b * NSPLIT + kvh) * SEQ;
  #pragma unroll
  for (int r = 0; r < 4; r++) {
    float s = ll[r];
    s += __shfl_xor(s, 1); s += __shfl_xor(s, 2);
    s += __shfl_xor(s, 4); s += __shfl_xor(s, 8);
    int row = qrow0 + lg * 4 + r;
    if (l15 == 0) llp[pbase + row] = s;
    __half* op = pacc + (pbase + row) * CCH + l15;
    #pragma unroll
    for (int dt = 0; dt < 16; dt++) op[dt * 16] = __float2half(oacc[dt][r]);
  }
}

// ---------------- combine: sum NSPLIT partials / sum lls -> aob bf16 [b][s][c] --------
template<int NSPLIT>
__global__ __launch_bounds__(256) void combine(
    const __half* __restrict__ pacc, const float* __restrict__ llp,
    unsigned short* __restrict__ aob)
{
  int idx = blockIdx.x * 256 + threadIdx.x;
  int c4 = idx & 63;
  int srow = idx >> 6;
  int b = srow >> 12, s = srow & 4095;
  float den = 0.f;
  float acc[4] = {0.f, 0.f, 0.f, 0.f};
  #pragma unroll
  for (int k = 0; k < NSPLIT; k++) {
    size_t pb = (size_t)(b * NSPLIT + k) * SEQ + s;
    den += llp[pb];
    const __half* p = pacc + pb * CCH + c4 * 4;
    #pragma unroll
    for (int j = 0; j < 4; j++) acc[j] += __half2float(p[j]);
  }
  float inv = 1.f / den;
  u16x4 r;
  #pragma unroll
  for (int j = 0; j < 4; j++) ((unsigned short*)&r)[j] = f2bf(acc[j] * inv);
  *(u16x4*)&aob[((size_t)b * SEQ + s) * CCH + c4 * 4] = r;
}

// ---------------- out_proj: block = 32 s; wave w -> 64 out-ch; + bias + residual ------
__global__ __launch_bounds__(256) void out_proj(
    const unsigned short* __restrict__ aob, const unsigned short* __restrict__ wb,
    const float* __restrict__ bias, const float* __restrict__ x,
    float* __restrict__ out)
{
  int b = blockIdx.y, st = blockIdx.x;   // st 0..127
  int tid = threadIdx.x, w = tid >> 6, l = tid & 63, l15 = l & 15, lg = l >> 4;
  int sbase = st * 32, obase = w * 64;

  f32x4 acc[4][2];
  #pragma unroll
  for (int i = 0; i < 4; i++)
    #pragma unroll
    for (int j = 0; j < 2; j++) acc[i][j] = (f32x4){0.f, 0.f, 0.f, 0.f};

  const unsigned short* aorow = aob + ((size_t)b * SEQ + sbase) * CCH;
  #pragma unroll
  for (int kt = 0; kt < 8; kt++) {
    s16x8 af[4], bfr[2];
    #pragma unroll
    for (int ot = 0; ot < 4; ot++)
      af[ot] = *(const s16x8*)&wb[(obase + ot * 16 + l15) * CCH + kt * 32 + lg * 8];
    #pragma unroll
    for (int sj = 0; sj < 2; sj++)
      bfr[sj] = *(const s16x8*)&aorow[(size_t)(sj * 16 + l15) * CCH + kt * 32 + lg * 8];
    #pragma unroll
    for (int ot = 0; ot < 4; ot++)
      #pragma unroll
      for (int sj = 0; sj < 2; sj++)
        acc[ot][sj] = __builtin_amdgcn_mfma_f32_16x16x32_bf16(af[ot], bfr[sj], acc[ot][sj], 0, 0, 0);
  }

  #pragma unroll
  for (int ot = 0; ot < 4; ot++) {
    #pragma unroll
    for (int r = 0; r < 4; r++) {
      int o = obase + ot * 16 + lg * 4 + r;
      float bi = bias[o];
      #pragma unroll
      for (int sj = 0; sj < 2; sj++) {
        int s = sbase + sj * 16 + l15;
        size_t idx = ((size_t)b * CCH + o) * SEQ + s;
        out[idx] = acc[ot][sj][r] + bi + x[idx];
      }
    }
  }
}

extern "C" void kernel_launch(void* const* d_in, const int* in_sizes, int n_in,
                              void* d_out, int out_size, void* d_ws, size_t ws_size,
                              hipStream_t stream) {
  const float* x     = (const float*)d_in[0];
  const float* w_qkv = (const float*)d_in[1];
  const float* b_qkv = (const float*)d_in[2];
  const float* w_out = (const float*)d_in[3];
  const float* b_out = (const float*)d_in[4];
  float* out = (float*)d_out;

  // ws: xb 0 | qb 8 | kb 16 | vb 24 | aob 32 | wqkb 40 | wob 40.5 | llp 41 | pacc 42..
  char* ws = (char*)d_ws;
  unsigned short* xbp  = (unsigned short*)(ws);
  unsigned short* qbp  = (unsigned short*)(ws + ((size_t)8 << 20));
  unsigned short* kbp  = (unsigned short*)(ws + ((size_t)16 << 20));
  unsigned short* vbp  = (unsigned short*)(ws + ((size_t)24 << 20));
  unsigned short* aob  = (unsigned short*)(ws + ((size_t)32 << 20));
  unsigned short* wqkb = (unsigned short*)(ws + ((size_t)40 << 20));
  unsigned short* wob  = (unsigned short*)(ws + ((size_t)40 << 20) + (512u << 10));
  float*          llp  = (float*)(ws + ((size_t)41 << 20));
  __half*         pacc = (__half*)(ws + ((size_t)42 << 20));

  cvt_w<<<dim3(192), 256, 0, stream>>>(w_qkv, wqkb);
  cvt_w<<<dim3(64), 256, 0, stream>>>(w_out, wob);
  cvt_x<<<dim3(64, 4, NB), 256, 0, stream>>>(x, xbp);
  qk_proj<<<dim3(128, NB), 256, 0, stream>>>(xbp, wqkb, b_qkv, qbp, kbp);
  v_proj<<<dim3(128, NB), 256, 0, stream>>>(xbp, wqkb, b_qkv, vbp);

  // pacc(split4) ends at 42MB + 33.6MB = 75.6MB; fall back to split2 if ws too small
  bool split4 = ws_size >= ((size_t)76 << 20);
  if (split4) {
    attn_kernel<4><<<dim3(64, 4, NB), 256, 0, stream>>>(qbp, kbp, vbp, pacc, llp);
    combine<4><<<dim3(4096), 256, 0, stream>>>(pacc, llp, aob);
  } else {
    attn_kernel<2><<<dim3(64, 2, NB), 256, 0, stream>>>(qbp, kbp, vbp, pacc, llp);
    combine<2><<<dim3(4096), 256, 0, stream>>>(pacc, llp, aob);
  }
  out_proj<<<dim3(128, NB), 256, 0, stream>>>(aob, wob, b_out, x, out);
}

// Round 5
// 202.417 us; speedup vs baseline: 2.4455x; 2.4455x over previous
//
#include <hip/hip_runtime.h>
#include <hip/hip_bf16.h>
#include <hip/hip_fp16.h>
#include <math.h>

typedef short s16x8 __attribute__((ext_vector_type(8)));
typedef float f32x4 __attribute__((ext_vector_type(4)));
typedef unsigned short u16x4 __attribute__((ext_vector_type(4)));

#define CCH 256
#define SEQ 4096
#define NB 4
#define KVB 32
#define NSPLIT 2
#define KVLEN (SEQ / NSPLIT)
#define NT (KVLEN / KVB)

static __device__ __forceinline__ unsigned short f2bf(float f) {
  union { float f; unsigned int u; } v; v.f = f;
  unsigned int u = v.u;
  unsigned int r = u + 0x7FFFu + ((u >> 16) & 1u);   // RNE
  return (unsigned short)(r >> 16);
}

static __device__ __forceinline__ void gl16(const void* g, void* l) {
  __builtin_amdgcn_global_load_lds(
      (const __attribute__((address_space(1))) void*)g,
      (__attribute__((address_space(3))) void*)l, 16, 0, 0);
}

// ---------------- cvt_w: fp32 -> bf16, 4 elems/thread ----------------
__global__ __launch_bounds__(256) void cvt_w(const float* __restrict__ w,
                                             unsigned short* __restrict__ wb) {
  int i = blockIdx.x * 256 + threadIdx.x;
  float4 v = ((const float4*)w)[i];
  u16x4 r;
  r.x = f2bf(v.x); r.y = f2bf(v.y); r.z = f2bf(v.z); r.w = f2bf(v.w);
  ((u16x4*)wb)[i] = r;
}

// ---------------- cvt_x: x[b][c][s] fp32 -> xb[b][s][c] bf16 (LDS transpose) ------
__global__ __launch_bounds__(256) void cvt_x(const float* __restrict__ x,
                                             unsigned short* __restrict__ xb) {
  __shared__ unsigned short T[64][72];
  int b = blockIdx.z, ct = blockIdx.y, st = blockIdx.x;
  int c0 = ct * 64, s0 = st * 64;
  int tid = threadIdx.x;
  #pragma unroll
  for (int i = 0; i < 4; i++) {
    int idx = tid + i * 256;
    int cr = idx >> 4, c4 = idx & 15;
    float4 v = *(const float4*)&x[((size_t)b * CCH + c0 + cr) * SEQ + s0 + c4 * 4];
    #pragma unroll
    for (int j = 0; j < 4; j++) {
      int s = c4 * 4 + j;
      int colp = cr ^ ((((s) >> 1) & 7) << 3);
      float fv = (j == 0) ? v.x : (j == 1) ? v.y : (j == 2) ? v.z : v.w;
      T[s][colp] = f2bf(fv);
    }
  }
  __syncthreads();
  #pragma unroll
  for (int i = 0; i < 2; i++) {
    int idx = tid + i * 256;
    int sr = idx >> 3, ch = idx & 7;
    int chp = ch ^ ((sr >> 1) & 7);
    s16x8 v = *(const s16x8*)&T[sr][chp * 8];
    *(s16x8*)&xb[((size_t)b * SEQ + s0 + sr) * CCH + c0 + ch * 8] = v;
  }
}

// ---------------- qk_proj: block = 32 s-rows; waves 0,1 -> q, waves 2,3 -> k ----------
__global__ __launch_bounds__(256) void qk_proj(
    const unsigned short* __restrict__ xb, const unsigned short* __restrict__ wqkb,
    const float* __restrict__ bias,
    unsigned short* __restrict__ qb, unsigned short* __restrict__ kb)
{
  int b = blockIdx.y, st = blockIdx.x;   // st 0..127
  int tid = threadIdx.x, w = tid >> 6, l = tid & 63, l15 = l & 15, lg = l >> 4;
  int row0 = st * 32 + (w & 1) * 16;
  int osel = w >> 1;                     // 0=q 1=k

  const unsigned short* xp = xb + ((size_t)b * SEQ + row0 + l15) * CCH + lg * 8;
  s16x8 af[8];
  #pragma unroll
  for (int t = 0; t < 8; t++) af[t] = *(const s16x8*)(xp + t * 32);

  unsigned short* dst = osel ? kb : qb;
  #pragma unroll
  for (int ot = 0; ot < 16; ot++) {
    int orow = osel * 256 + ot * 16;
    f32x4 acc = (f32x4){0.f, 0.f, 0.f, 0.f};
    #pragma unroll
    for (int t = 0; t < 8; t++) {
      s16x8 wf = *(const s16x8*)&wqkb[(size_t)(orow + l15) * CCH + t * 32 + lg * 8];
      acc = __builtin_amdgcn_mfma_f32_16x16x32_bf16(af[t], wf, acc, 0, 0, 0);
    }
    float bi = bias[orow + l15];
    int ch = ot * 16 + l15;
    #pragma unroll
    for (int r = 0; r < 4; r++) {
      int srow = row0 + lg * 4 + r;
      dst[((size_t)b * SEQ + srow) * CCH + ch] = f2bf(acc[r] + bi);
    }
  }
}

// ---------------- v_proj: block = 32 s; wave w -> 64 out-ch; v -> [b][c][s] ----------
__global__ __launch_bounds__(256) void v_proj(
    const unsigned short* __restrict__ xb, const unsigned short* __restrict__ wqkb,
    const float* __restrict__ bias, unsigned short* __restrict__ vb)
{
  int b = blockIdx.y, st = blockIdx.x;   // st 0..127
  int tid = threadIdx.x, w = tid >> 6, l = tid & 63, l15 = l & 15, lg = l >> 4;
  int sbase = st * 32, obase = w * 64;

  f32x4 acc[4][2];
  #pragma unroll
  for (int i = 0; i < 4; i++)
    #pragma unroll
    for (int j = 0; j < 2; j++) acc[i][j] = (f32x4){0.f, 0.f, 0.f, 0.f};

  const unsigned short* xrow = xb + ((size_t)b * SEQ + sbase) * CCH;
  #pragma unroll
  for (int kt = 0; kt < 8; kt++) {
    s16x8 afr[4], bfr[2];
    #pragma unroll
    for (int ot = 0; ot < 4; ot++)
      afr[ot] = *(const s16x8*)&wqkb[(size_t)(512 + obase + ot * 16 + l15) * CCH + kt * 32 + lg * 8];
    #pragma unroll
    for (int sj = 0; sj < 2; sj++)
      bfr[sj] = *(const s16x8*)&xrow[(size_t)(sj * 16 + l15) * CCH + kt * 32 + lg * 8];
    #pragma unroll
    for (int ot = 0; ot < 4; ot++)
      #pragma unroll
      for (int sj = 0; sj < 2; sj++)
        acc[ot][sj] = __builtin_amdgcn_mfma_f32_16x16x32_bf16(afr[ot], bfr[sj], acc[ot][sj], 0, 0, 0);
  }

  #pragma unroll
  for (int ot = 0; ot < 4; ot++) {
    #pragma unroll
    for (int r = 0; r < 4; r++) {
      int o = obase + ot * 16 + lg * 4 + r;
      float bi = bias[512 + o];
      #pragma unroll
      for (int sj = 0; sj < 2; sj++) {
        int s = sbase + sj * 16 + l15;
        vb[((size_t)b * CCH + o) * SEQ + s] = f2bf(acc[ot][sj][r] + bi);
      }
    }
  }
}

// ---------------- attn: dbuf LDS (round-3 proven) + swapped QK^T + packed P writes ----
// 256 threads = 4 waves; wave owns 16 query rows; KV tiles of 32 keys; KV-split x2.
// Swapped QK^T: sacc = mfma(K,Q) -> lane holds P[key=lg*4+r][q=l15]; P^T pack -> b64.
__global__ __launch_bounds__(256) void attn_kernel(
    const unsigned short* __restrict__ qb,
    const unsigned short* __restrict__ kb,
    const unsigned short* __restrict__ vb,
    __half* __restrict__ pacc, float* __restrict__ llp)
{
  __shared__ __align__(16) unsigned short Ks[2][KVB * CCH];   // 2 x 16KB
  __shared__ __align__(16) unsigned short Vs[2][CCH * KVB];   // 2 x 16KB
  __shared__ __align__(16) unsigned short plds[4][16][40];    // per-wave P tile [q][key]

  int b = blockIdx.z, kvh = blockIdx.y, qt = blockIdx.x;
  int tid = threadIdx.x, w = tid >> 6, l = tid & 63;
  int l15 = l & 15, lg = l >> 4, s3 = l15 & 7;

  int qrow0 = qt * 64 + w * 16;
  const unsigned short* qptr = qb + ((size_t)b * SEQ + qrow0 + l15) * CCH + lg * 8;
  s16x8 qf[8];
  #pragma unroll
  for (int t = 0; t < 8; t++) qf[t] = *(const s16x8*)(qptr + t * 32);

  f32x4 oacc[16];
  #pragma unroll
  for (int i = 0; i < 16; i++) oacc[i] = (f32x4){0.f, 0.f, 0.f, 0.f};
  float ll = 0.f;   // per-lane partial row-sum for query q = l15

  int koff[4], voff[4];
  #pragma unroll
  for (int i = 0; i < 4; i++) {
    int idx = i * 256 + tid;
    int r = idx >> 5, c = idx & 31;
    koff[i] = r * CCH + (c ^ (r & 7)) * 8;
    int ch = idx >> 2, c2 = idx & 3;
    voff[i] = ch * SEQ + (c2 ^ (ch & 3)) * 8;
  }
  const unsigned short* kbb = kb + (size_t)b * SEQ * CCH + (size_t)kvh * KVLEN * CCH;
  const unsigned short* vbb = vb + (size_t)b * CCH * SEQ + kvh * KVLEN;

  auto stage = [&](int buf, int kv) {
    size_t kofs = (size_t)kv * KVB * CCH;
    int    vofs = kv * KVB;
    #pragma unroll
    for (int i = 0; i < 4; i++) {
      int idx = i * 256 + tid;
      gl16(kbb + kofs + koff[i], &Ks[buf][idx * 8]);
    }
    #pragma unroll
    for (int i = 0; i < 4; i++) {
      int idx = i * 256 + tid;
      gl16(vbb + vofs + voff[i], &Vs[buf][idx * 8]);
    }
  };

  stage(0, 0);
  __syncthreads();

  int buf = 0;
  for (int kv = 0; kv < NT; kv++) {
    if (kv + 1 < NT) stage(buf ^ 1, kv + 1);

    // ---- QK^T swapped: A=K rows, B=Q cols -> D[key][query] ----
    f32x4 sacc[2];
    sacc[0] = (f32x4){0.f, 0.f, 0.f, 0.f};
    sacc[1] = (f32x4){0.f, 0.f, 0.f, 0.f};
    __builtin_amdgcn_s_setprio(1);
    #pragma unroll
    for (int kt = 0; kt < 2; kt++) {
      int rowoff = (kt * 16 + l15) * CCH;
      #pragma unroll
      for (int tt = 0; tt < 8; tt++) {
        s16x8 kf = *(const s16x8*)&Ks[buf][rowoff + (((tt * 4 + lg) ^ s3)) * 8];
        sacc[kt] = __builtin_amdgcn_mfma_f32_16x16x32_bf16(kf, qf[tt], sacc[kt], 0, 0, 0);
      }
    }
    __builtin_amdgcn_s_setprio(0);

    // ---- fixed-shift softmax + packed P^T write (2 x ds_write_b64 per lane) ----
    #pragma unroll
    for (int kt = 0; kt < 2; kt++) {
      u16x4 pk;
      #pragma unroll
      for (int r = 0; r < 4; r++) {
        float p = exp2f(fmaf(sacc[kt][r], 0.09016844f, -11.5415602f));
        ll += p;
        ((unsigned short*)&pk)[r] = f2bf(p);
      }
      *(u16x4*)&plds[w][l15][kt * 16 + lg * 4] = pk;
    }

    // ---- PV: A = P[q][key] (row=l15, keys lg*8..+8 contiguous) ----
    s16x8 pa = *(const s16x8*)&plds[w][l15][lg * 8];
    __builtin_amdgcn_s_setprio(1);
    #pragma unroll
    for (int dt = 0; dt < 16; dt++) {
      s16x8 vf = *(const s16x8*)&Vs[buf][(dt * 16 + l15) * KVB + ((lg ^ (l15 & 3)) * 8)];
      oacc[dt] = __builtin_amdgcn_mfma_f32_16x16x32_bf16(pa, vf, oacc[dt], 0, 0, 0);
    }
    __builtin_amdgcn_s_setprio(0);

    __syncthreads();
    buf ^= 1;
  }

  // ---- epilogue: reduce ll across lg groups (same l15), redistribute, store ----
  ll += __shfl_xor(ll, 16);
  ll += __shfl_xor(ll, 32);   // all lanes now hold full sum for q = l15
  size_t pbase = (size_t)(b * NSPLIT + kvh) * SEQ;
  if (lg == 0) llp[pbase + qrow0 + l15] = ll;
  float inv[4];
  #pragma unroll
  for (int r = 0; r < 4; r++) inv[r] = __shfl(ll, lg * 4 + r);   // ll for q = lg*4+r
  #pragma unroll
  for (int r = 0; r < 4; r++) {
    int row = qrow0 + lg * 4 + r;
    __half* op = pacc + (pbase + row) * CCH + l15;
    #pragma unroll
    for (int dt = 0; dt < 16; dt++) op[dt * 16] = __float2half(oacc[dt][r]);
  }
  (void)inv;  // inv kept for clarity; normalization happens in combine via llp
}

// ---------------- combine: sum NSPLIT partials / sum lls -> aob bf16 [b][s][c] --------
__global__ __launch_bounds__(256) void combine(
    const __half* __restrict__ pacc, const float* __restrict__ llp,
    unsigned short* __restrict__ aob)
{
  int idx = blockIdx.x * 256 + threadIdx.x;
  int c4 = idx & 63;
  int srow = idx >> 6;
  int b = srow >> 12, s = srow & 4095;
  float den = 0.f;
  float acc[4] = {0.f, 0.f, 0.f, 0.f};
  #pragma unroll
  for (int k = 0; k < NSPLIT; k++) {
    size_t pb = (size_t)(b * NSPLIT + k) * SEQ + s;
    den += llp[pb];
    const __half* p = pacc + pb * CCH + c4 * 4;
    #pragma unroll
    for (int j = 0; j < 4; j++) acc[j] += __half2float(p[j]);
  }
  float inv = 1.f / den;
  u16x4 r;
  #pragma unroll
  for (int j = 0; j < 4; j++) ((unsigned short*)&r)[j] = f2bf(acc[j] * inv);
  *(u16x4*)&aob[((size_t)b * SEQ + s) * CCH + c4 * 4] = r;
}

// ---------------- out_proj: block = 32 s; wave w -> 64 out-ch; + bias + residual ------
__global__ __launch_bounds__(256) void out_proj(
    const unsigned short* __restrict__ aob, const unsigned short* __restrict__ wb,
    const float* __restrict__ bias, const float* __restrict__ x,
    float* __restrict__ out)
{
  int b = blockIdx.y, st = blockIdx.x;   // st 0..127
  int tid = threadIdx.x, w = tid >> 6, l = tid & 63, l15 = l & 15, lg = l >> 4;
  int sbase = st * 32, obase = w * 64;

  f32x4 acc[4][2];
  #pragma unroll
  for (int i = 0; i < 4; i++)
    #pragma unroll
    for (int j = 0; j < 2; j++) acc[i][j] = (f32x4){0.f, 0.f, 0.f, 0.f};

  const unsigned short* aorow = aob + ((size_t)b * SEQ + sbase) * CCH;
  #pragma unroll
  for (int kt = 0; kt < 8; kt++) {
    s16x8 af[4], bfr[2];
    #pragma unroll
    for (int ot = 0; ot < 4; ot++)
      af[ot] = *(const s16x8*)&wb[(obase + ot * 16 + l15) * CCH + kt * 32 + lg * 8];
    #pragma unroll
    for (int sj = 0; sj < 2; sj++)
      bfr[sj] = *(const s16x8*)&aorow[(size_t)(sj * 16 + l15) * CCH + kt * 32 + lg * 8];
    #pragma unroll
    for (int ot = 0; ot < 4; ot++)
      #pragma unroll
      for (int sj = 0; sj < 2; sj++)
        acc[ot][sj] = __builtin_amdgcn_mfma_f32_16x16x32_bf16(af[ot], bfr[sj], acc[ot][sj], 0, 0, 0);
  }

  #pragma unroll
  for (int ot = 0; ot < 4; ot++) {
    #pragma unroll
    for (int r = 0; r < 4; r++) {
      int o = obase + ot * 16 + lg * 4 + r;
      float bi = bias[o];
      #pragma unroll
      for (int sj = 0; sj < 2; sj++) {
        int s = sbase + sj * 16 + l15;
        size_t idx = ((size_t)b * CCH + o) * SEQ + s;
        out[idx] = acc[ot][sj][r] + bi + x[idx];
      }
    }
  }
}

extern "C" void kernel_launch(void* const* d_in, const int* in_sizes, int n_in,
                              void* d_out, int out_size, void* d_ws, size_t ws_size,
                              hipStream_t stream) {
  const float* x     = (const float*)d_in[0];
  const float* w_qkv = (const float*)d_in[1];
  const float* b_qkv = (const float*)d_in[2];
  const float* w_out = (const float*)d_in[3];
  const float* b_out = (const float*)d_in[4];
  float* out = (float*)d_out;

  // ws: xb 0 | qb 8 | kb 16 | vb 24 | aob 32 | wqkb 40 | wob 40.5 | llp 41 | pacc 42..59
  char* ws = (char*)d_ws;
  unsigned short* xbp  = (unsigned short*)(ws);
  unsigned short* qbp  = (unsigned short*)(ws + ((size_t)8 << 20));
  unsigned short* kbp  = (unsigned short*)(ws + ((size_t)16 << 20));
  unsigned short* vbp  = (unsigned short*)(ws + ((size_t)24 << 20));
  unsigned short* aob  = (unsigned short*)(ws + ((size_t)32 << 20));
  unsigned short* wqkb = (unsigned short*)(ws + ((size_t)40 << 20));
  unsigned short* wob  = (unsigned short*)(ws + ((size_t)40 << 20) + (512u << 10));
  float*          llp  = (float*)(ws + ((size_t)41 << 20));
  __half*         pacc = (__half*)(ws + ((size_t)42 << 20));

  cvt_w<<<dim3(192), 256, 0, stream>>>(w_qkv, wqkb);
  cvt_w<<<dim3(64), 256, 0, stream>>>(w_out, wob);
  cvt_x<<<dim3(64, 4, NB), 256, 0, stream>>>(x, xbp);
  qk_proj<<<dim3(128, NB), 256, 0, stream>>>(xbp, wqkb, b_qkv, qbp, kbp);
  v_proj<<<dim3(128, NB), 256, 0, stream>>>(xbp, wqkb, b_qkv, vbp);
  attn_kernel<<<dim3(64, NSPLIT, NB), 256, 0, stream>>>(qbp, kbp, vbp, pacc, llp);
  combine<<<dim3(4096), 256, 0, stream>>>(pacc, llp, aob);
  out_proj<<<dim3(128, NB), 256, 0, stream>>>(aob, wob, b_out, x, out);
}